// Round 10
// baseline (621.412 us; speedup 1.0000x reference)
//
#include <hip/hip_runtime.h>
#include <math.h>

#define NTOK 6272   // B*H*W = 32*14*14

typedef __attribute__((ext_vector_type(8))) short short8;
typedef __attribute__((ext_vector_type(8))) unsigned short ushort8;
typedef __attribute__((ext_vector_type(4))) float f32x4;

__device__ __forceinline__ float sigmoidf_(float v){ return 1.0f/(1.0f + expf(-v)); }

// f32 -> bf16 round-to-nearest-even
__device__ __forceinline__ unsigned short f2b(float f){
  union { float f; unsigned u; } v; v.f = f;
  unsigned r = (v.u + 0x7fffu + ((v.u>>16)&1u)) >> 16;
  return (unsigned short)r;
}

// ---------------- f32 -> bf16 bulk convert (grid-stride, vectorized) ----------------
__global__ __launch_bounds__(256) void cvt_bf16_kernel(
    const float* __restrict__ src, unsigned short* __restrict__ dst, int n8)
{
  int i = blockIdx.x*256 + threadIdx.x;
  int stride = gridDim.x*256;
  for (; i < n8; i += stride){
    float4 a = *(const float4*)(src + (size_t)i*8);
    float4 b = *(const float4*)(src + (size_t)i*8 + 4);
    ushort8 o;
    o[0]=f2b(a.x); o[1]=f2b(a.y); o[2]=f2b(a.z); o[3]=f2b(a.w);
    o[4]=f2b(b.x); o[5]=f2b(b.y); o[6]=f2b(b.z); o[7]=f2b(b.w);
    *(ushort8*)(dst + (size_t)i*8) = o;
  }
}

// ---------------- gating: logits -> softmax -> top2 -> comb + avg/load sums ----------------
__global__ __launch_bounds__(256) void gate_kernel(
    const float* __restrict__ x, const float* __restrict__ eq,
    const float* __restrict__ temp, float* __restrict__ comb,
    float* __restrict__ avgsum, float* __restrict__ loadsum)
{
  __shared__ float lacc[8];
  if (threadIdx.x < 8) lacc[threadIdx.x] = 0.f;
  __syncthreads();
  int wid = threadIdx.x >> 6, lane = threadIdx.x & 63;
  int m = blockIdx.x*4 + wid;             // token index
  const float* xr = x + (size_t)m*512;
  float a0=0.f,a1=0.f,a2=0.f,a3=0.f;
  #pragma unroll
  for (int j=0;j<8;++j){
    float xv = xr[j*64+lane];
    a0 = fmaf(xv, eq[0*512 + j*64+lane], a0);
    a1 = fmaf(xv, eq[1*512 + j*64+lane], a1);
    a2 = fmaf(xv, eq[2*512 + j*64+lane], a2);
    a3 = fmaf(xv, eq[3*512 + j*64+lane], a3);
  }
  #pragma unroll
  for (int off=32; off; off>>=1){
    a0 += __shfl_xor(a0,off); a1 += __shfl_xor(a1,off);
    a2 += __shfl_xor(a2,off); a3 += __shfl_xor(a3,off);
  }
  if (lane == 0){
    float T = temp[0];
    float l0=a0/T, l1=a1/T, l2=a2/T, l3=a3/T;
    float mx = fmaxf(fmaxf(l0,l1), fmaxf(l2,l3));
    float e0=expf(l0-mx), e1=expf(l1-mx), e2=expf(l2-mx), e3=expf(l3-mx);
    float s = e0+e1+e2+e3;
    float g0=e0/s, g1=e1/s, g2=e2/s, g3=e3/s;
    int i1=0; float v1=g0;
    if (g1>v1){v1=g1;i1=1;}
    if (g2>v1){v1=g2;i1=2;}
    if (g3>v1){v1=g3;i1=3;}
    int i2=-1; float v2=-2.f;
    if (i1!=0)          {v2=g0;i2=0;}
    if (i1!=1 && g1>v2) {v2=g1;i2=1;}
    if (i1!=2 && g2>v2) {v2=g2;i2=2;}
    if (i1!=3 && g3>v2) {v2=g3;i2=3;}
    float inv = 1.f/(v1+v2);
    float c0 = (i1==0)? v1*inv : ((i2==0)? v2*inv : 0.f);
    float c1 = (i1==1)? v1*inv : ((i2==1)? v2*inv : 0.f);
    float c2 = (i1==2)? v1*inv : ((i2==2)? v2*inv : 0.f);
    float c3 = (i1==3)? v1*inv : ((i2==3)? v2*inv : 0.f);
    comb[(size_t)m*4+0]=c0; comb[(size_t)m*4+1]=c1;
    comb[(size_t)m*4+2]=c2; comb[(size_t)m*4+3]=c3;
    atomicAdd(&lacc[0], g0); atomicAdd(&lacc[1], g1);
    atomicAdd(&lacc[2], g2); atomicAdd(&lacc[3], g3);
    atomicAdd(&lacc[4+i1], 0.5f);
    atomicAdd(&lacc[4+i2], 0.5f);
  }
  __syncthreads();
  if (threadIdx.x < 4){
    atomicAdd(&avgsum[threadIdx.x],  lacc[threadIdx.x]);
    atomicAdd(&loadsum[threadIdx.x], lacc[4+threadIdx.x]);
  }
}

__global__ void aux_kernel(const float* __restrict__ avgsum,
                           const float* __restrict__ loadsum,
                           float* __restrict__ out_aux)
{
  if (threadIdx.x == 0 && blockIdx.x == 0){
    float s = 0.f;
    #pragma unroll
    for (int e=0;e<4;++e)
      s += (avgsum[e]/(float)NTOK) * (loadsum[e]/(float)NTOK);
    out_aux[0] = 0.01f * (s * 0.25f) * 16.0f;
  }
}

// ---------------- in_proj GEMM, bf16 inputs, 128x128 tile (tier 1) ----------------
__global__ __launch_bounds__(256) void gemm_bf16(
    const unsigned short* __restrict__ A, const unsigned short* __restrict__ W,
    float* __restrict__ C)
{
  __shared__ unsigned short As[128][56];
  __shared__ unsigned short Bs[128][56];
  const unsigned short* We = W + (size_t)blockIdx.z*524288;
  float* Ce = C + (size_t)blockIdx.z*6422528;
  int m0 = blockIdx.x*128, n0 = blockIdx.y*128;
  int t = threadIdx.x;
  int srow = t>>1, scol = (t&1)*16;
  int w = t>>6, lane = t&63;
  int wr = (w>>1)*64, wc = (w&1)*64;
  int fr = lane&15, fk = (lane>>4)*8;
  f32x4 acc[4][4] = {};
  const unsigned short* ap = A  + (size_t)(m0+srow)*512 + scol;
  const unsigned short* bp = We + (size_t)(n0+srow)*512 + scol;
  for (int k0=0; k0<512; k0+=32){
    ushort8 va0 = *(const ushort8*)(ap+k0);
    ushort8 va1 = *(const ushort8*)(ap+k0+8);
    ushort8 vb0 = *(const ushort8*)(bp+k0);
    ushort8 vb1 = *(const ushort8*)(bp+k0+8);
    __syncthreads();
    *(ushort8*)&As[srow][scol]   = va0;
    *(ushort8*)&As[srow][scol+8] = va1;
    *(ushort8*)&Bs[srow][scol]   = vb0;
    *(ushort8*)&Bs[srow][scol+8] = vb1;
    __syncthreads();
    short8 af[4], bf[4];
    #pragma unroll
    for (int i=0;i<4;++i){
      af[i] = *(short8*)&As[wr+i*16+fr][fk];
      bf[i] = *(short8*)&Bs[wc+i*16+fr][fk];
    }
    #pragma unroll
    for (int i=0;i<4;++i)
      #pragma unroll
      for (int j=0;j<4;++j)
        acc[i][j] = __builtin_amdgcn_mfma_f32_16x16x32_bf16(af[i],bf[j],acc[i][j],0,0,0);
  }
  int orow = (lane>>4)*4;   // C/D: col=lane&15, row=(lane>>4)*4+reg  [m89-verified]
  #pragma unroll
  for (int i=0;i<4;++i)
    #pragma unroll
    for (int j=0;j<4;++j)
      #pragma unroll
      for (int r=0;r<4;++r)
        Ce[(size_t)(m0+wr+i*16+orow+r)*1024 + n0+wc+j*16+fr] = acc[i][j][r];
}

// ---------------- in_proj GEMM, in-loop f32->bf16 (tier 2/3 fallback) ----------------
__global__ __launch_bounds__(256) void gemm_mfma(
    const float* __restrict__ A, const float* __restrict__ W,
    float* __restrict__ C, size_t wStride, size_t cStride)
{
  __shared__ unsigned short As[64][56];
  __shared__ unsigned short Bs[64][56];
  const float* We = W + (size_t)blockIdx.z*wStride;
  float* Ce = C + (size_t)blockIdx.z*cStride;
  int m0 = blockIdx.x*64, n0 = blockIdx.y*64;
  int t = threadIdx.x;
  int srow = t>>2, scol = (t&3)*8;
  int w = t>>6, lane = t&63;
  int wr = (w>>1)*32, wc = (w&1)*32;
  int fr = lane&15, fk = (lane>>4)*8;
  f32x4 acc00={0.f,0.f,0.f,0.f}, acc01={0.f,0.f,0.f,0.f};
  f32x4 acc10={0.f,0.f,0.f,0.f}, acc11={0.f,0.f,0.f,0.f};
  const float* ap = A  + (size_t)(m0+srow)*512 + scol;
  const float* bp = We + (size_t)(n0+srow)*512 + scol;
  for (int k0=0; k0<512; k0+=32){
    float4 av0 = *(const float4*)(ap+k0);
    float4 av1 = *(const float4*)(ap+k0+4);
    float4 bv0 = *(const float4*)(bp+k0);
    float4 bv1 = *(const float4*)(bp+k0+4);
    ushort8 va, vb;
    va[0]=f2b(av0.x); va[1]=f2b(av0.y); va[2]=f2b(av0.z); va[3]=f2b(av0.w);
    va[4]=f2b(av1.x); va[5]=f2b(av1.y); va[6]=f2b(av1.z); va[7]=f2b(av1.w);
    vb[0]=f2b(bv0.x); vb[1]=f2b(bv0.y); vb[2]=f2b(bv0.z); vb[3]=f2b(bv0.w);
    vb[4]=f2b(bv1.x); vb[5]=f2b(bv1.y); vb[6]=f2b(bv1.z); vb[7]=f2b(bv1.w);
    __syncthreads();
    *(ushort8*)&As[srow][scol] = va;
    *(ushort8*)&Bs[srow][scol] = vb;
    __syncthreads();
    short8 a0 = *(short8*)&As[wr+fr][fk];
    short8 a1 = *(short8*)&As[wr+16+fr][fk];
    short8 b0 = *(short8*)&Bs[wc+fr][fk];
    short8 b1 = *(short8*)&Bs[wc+16+fr][fk];
    acc00 = __builtin_amdgcn_mfma_f32_16x16x32_bf16(a0,b0,acc00,0,0,0);
    acc01 = __builtin_amdgcn_mfma_f32_16x16x32_bf16(a0,b1,acc01,0,0,0);
    acc10 = __builtin_amdgcn_mfma_f32_16x16x32_bf16(a1,b0,acc10,0,0,0);
    acc11 = __builtin_amdgcn_mfma_f32_16x16x32_bf16(a1,b1,acc11,0,0,0);
  }
  int orow = (lane>>4)*4;
  #pragma unroll
  for (int r=0;r<4;++r){
    Ce[(size_t)(m0+wr+orow+r)*1024    + n0+wc+fr]    = acc00[r];
    Ce[(size_t)(m0+wr+orow+r)*1024    + n0+wc+16+fr] = acc01[r];
    Ce[(size_t)(m0+wr+16+orow+r)*1024 + n0+wc+fr]    = acc10[r];
    Ce[(size_t)(m0+wr+16+orow+r)*1024 + n0+wc+16+fr] = acc11[r];
  }
}

// ---------------- fused conv+proj, row-block form with XCD-chunked swizzle ----------------
__global__ __launch_bounds__(512) void convproj_kernel(
    const float* __restrict__ xz, const float* __restrict__ cw,
    const float* __restrict__ cb, const float* __restrict__ xw,
    float* __restrict__ xc, float* __restrict__ proj,
    size_t xzS, size_t xcS, size_t prS)
{
  __shared__ float sact[512];
  int chunk = gridDim.x >> 3;                    // grid divisible by 8
  int bid = blockIdx.x;
  int flat = (bid & 7)*chunk + (bid >> 3);       // XCD-chunked swizzle (bijective)
  int h  = flat % 14;
  int be = flat / 14;
  int b  = be & 31;
  int e  = be >> 5;
  const float* xze = xz + (size_t)e*xzS;
  const float* cwe = cw + (size_t)e*4608;
  const float* xwe = xw + (size_t)e*12288;
  float* xce = xc + (size_t)e*xcS;
  float* pre = proj + (size_t)e*prS;
  int d = threadIdx.x;
  int wv = d>>6, lane = d&63;
  int d0 = lane*8;

  float wreg[9];
  #pragma unroll
  for (int i=0;i<9;++i) wreg[i] = cwe[d*9+i];
  float bias = cb[(size_t)e*512 + d];

  const float* base = xze + ((size_t)b*196 + (size_t)h*14)*1024 + d;

  for (int w=0; w<14; ++w){
    float s = bias;
    #pragma unroll
    for (int dh=-1; dh<=1; ++dh){
      int hh = h+dh; if ((unsigned)hh >= 14u) continue;
      #pragma unroll
      for (int dw=-1; dw<=1; ++dw){
        int ww = w+dw; if ((unsigned)ww >= 14u) continue;
        s = fmaf(base[(ptrdiff_t)(dh*14 + ww)*1024], wreg[(dh+1)*3 + (dw+1)], s);
      }
    }
    float sa = s * sigmoidf_(s);
    size_t m = (size_t)b*196 + h*14 + w;
    xce[m*512 + d] = sa;
    __syncthreads();
    sact[d] = sa;
    __syncthreads();
    float4 v0 = *(const float4*)&sact[d0];
    float4 v1 = *(const float4*)&sact[d0+4];
    #pragma unroll
    for (int j=0;j<3;++j){
      int kc = wv*3 + j;
      const float* wr = xwe + (size_t)kc*512 + d0;
      float4 w0 = *(const float4*)(wr);
      float4 w1 = *(const float4*)(wr+4);
      float a = v0.x*w0.x + v0.y*w0.y + v0.z*w0.z + v0.w*w0.w
              + v1.x*w1.x + v1.y*w1.y + v1.z*w1.z + v1.w*w1.w;
      #pragma unroll
      for (int off=32; off; off>>=1) a += __shfl_xor(a,off);
      if (lane==0) pre[m*24 + kc] = a;
    }
  }
}

// ---------------- selective scan: block=(e,b,dgroup64), 4 k-waves, LDS merge ----------------
// No global atomics: the 4 directions accumulate into a shared [196][64] tile
// (LDS atomicAdd, conflict-free rows), then one cooperative coalesced store.
#define WRAP(v) ((v) > 195 ? (v)-195 : ((v) < 0 ? (v)+195 : (v)))

__global__ __launch_bounds__(256) void scan_kernel(
    const float* __restrict__ xc, const float* __restrict__ proj,
    const float* __restrict__ Alogs, const float* __restrict__ Dsp,
    const float* __restrict__ dtw, const float* __restrict__ dtb,
    float* __restrict__ ycomb,
    size_t xcS, size_t prS, size_t ycS)
{
  __shared__ float ytile[196*64];
  const float LN2 = 0.6931471805599453f;
  int bid = blockIdx.x;                  // (e<<8) | (b<<3) | dg
  int e  = bid >> 8;
  int b  = (bid >> 3) & 31;
  int dg = bid & 7;
  int k  = threadIdx.x >> 6;
  int dl = threadIdx.x & 63;
  int d  = dg*64 + dl;

  for (int i = threadIdx.x; i < 196*64; i += 256) ytile[i] = 0.f;
  __syncthreads();

  const float* xce = xc + (size_t)e*xcS;
  const float* pre = proj + (size_t)e*prS;
  float* yce = ycomb + (size_t)e*ycS;
  int eo = e*2048;
  float Ak  = -__expf(Alogs[eo + k*512 + d]);
  float Dk  = Dsp[eo + k*512 + d];
  float btk = dtb[eo + k*512 + d];
  const float* wr = dtw + (size_t)e*8192 + ((size_t)(k*512 + d))*4;
  float w0=wr[0], w1=wr[1], w2=wr[2], w3=wr[3];
  float hst = 0.f;
  const float* xcb = xce + (size_t)b*196*512 + d;
  const float* pb  = pre + (size_t)b*196*24 + k*6;

  int step = (k==0)? 1 : (k==1)? -1 : (k==2)? 14 : -14;
  int t0   = (k==0 || k==2)? 0 : 195;

  // group-of-4 software pipeline (unchanged recurrence)
  int ta=t0, tb_=WRAP(ta+step), tc=WRAP(tb_+step), td_=WRAP(tc+step);
  float  xa=xcb[ta*512],  xb=xcb[tb_*512],  xcv=xcb[tc*512],  xd=xcb[td_*512];
  float2 a0=*(const float2*)(pb+ta*24),  a1=*(const float2*)(pb+ta*24+2),  a2=*(const float2*)(pb+ta*24+4);
  float2 b0=*(const float2*)(pb+tb_*24), b1=*(const float2*)(pb+tb_*24+2), b2=*(const float2*)(pb+tb_*24+4);
  float2 c0=*(const float2*)(pb+tc*24),  c1=*(const float2*)(pb+tc*24+2),  c2=*(const float2*)(pb+tc*24+4);
  float2 d0=*(const float2*)(pb+td_*24), d1=*(const float2*)(pb+td_*24+2), d2=*(const float2*)(pb+td_*24+4);

#define STEP(tt, xv, f0, f1, f2)                                              \
  {                                                                           \
    float dtraw = btk + w0*f0.x + w1*f0.y + w2*f1.x + w3*f1.y;                \
    float sp = fmaxf(dtraw, 0.f) + LN2*__log2f(1.0f + __expf(-fabsf(dtraw))); \
    float dA = __expf(sp*Ak);                                                 \
    hst = fmaf(dA, hst, sp*xv*f2.x);                                          \
    float y = fmaf(hst, f2.y, xv*Dk);                                         \
    atomicAdd(&ytile[(tt)*64 + dl], y);                                       \
  }

  for (int gg=0; gg<48; ++gg){
    int na = WRAP(td_+step), nb = WRAP(na+step), nc = WRAP(nb+step), nd = WRAP(nc+step);
    float  nxa=xcb[na*512], nxb=xcb[nb*512], nxc=xcb[nc*512], nxd=xcb[nd*512];
    float2 qa0=*(const float2*)(pb+na*24), qa1=*(const float2*)(pb+na*24+2), qa2=*(const float2*)(pb+na*24+4);
    float2 qb0=*(const float2*)(pb+nb*24), qb1=*(const float2*)(pb+nb*24+2), qb2=*(const float2*)(pb+nb*24+4);
    float2 qc0=*(const float2*)(pb+nc*24), qc1=*(const float2*)(pb+nc*24+2), qc2=*(const float2*)(pb+nc*24+4);
    float2 qd0=*(const float2*)(pb+nd*24), qd1=*(const float2*)(pb+nd*24+2), qd2=*(const float2*)(pb+nd*24+4);

    STEP(ta, xa, a0, a1, a2)
    STEP(tb_, xb, b0, b1, b2)
    STEP(tc, xcv, c0, c1, c2)
    STEP(td_, xd, d0, d1, d2)

    ta=na; tb_=nb; tc=nc; td_=nd;
    xa=nxa; xb=nxb; xcv=nxc; xd=nxd;
    a0=qa0; a1=qa1; a2=qa2;
    b0=qb0; b1=qb1; b2=qb2;
    c0=qc0; c1=qc1; c2=qc2;
    d0=qd0; d1=qd1; d2=qd2;
  }
  STEP(ta, xa, a0, a1, a2)
  STEP(tb_, xb, b0, b1, b2)
  STEP(tc, xcv, c0, c1, c2)
  STEP(td_, xd, d0, d1, d2)
#undef STEP

  __syncthreads();
  // cooperative coalesced write-out of the merged tile (fully overwrites -> no memset)
  for (int i = threadIdx.x; i < 196*64; i += 256){
    int t = i >> 6, dc = i & 63;
    yce[((size_t)b*196 + t)*512 + dg*64 + dc] = ytile[i];
  }
}

// ---------------- LayerNorm + SiLU(z) gate + comb mix + token-mean (wave-per-token) ----------------
template<int NEXP>
__global__ __launch_bounds__(256) void final_kernel(
    const float* __restrict__ ycomb, size_t ycS,
    const float* __restrict__ xz, size_t xzS,
    const float* __restrict__ comb, const float* __restrict__ nw,
    const float* __restrict__ nb, float* __restrict__ out, int e0)
{
  int b = blockIdx.x;
  int wv = threadIdx.x>>6, lane = threadIdx.x&63;
  int t = blockIdx.y*4 + wv;             // 49*4 = 196 tokens
  size_t tok = (size_t)b*196 + t;
  int d0 = lane*8;
  float acc[8] = {0.f,0.f,0.f,0.f,0.f,0.f,0.f,0.f};
  #pragma unroll
  for (int i=0;i<NEXP;++i){
    const float* yp = ycomb + (size_t)i*ycS + tok*512 + d0;
    float4 y0 = *(const float4*)(yp);
    float4 y1 = *(const float4*)(yp+4);
    float s = y0.x+y0.y+y0.z+y0.w + y1.x+y1.y+y1.z+y1.w;
    float q = y0.x*y0.x+y0.y*y0.y+y0.z*y0.z+y0.w*y0.w
            + y1.x*y1.x+y1.y*y1.y+y1.z*y1.z+y1.w*y1.w;
    #pragma unroll
    for (int off=32; off; off>>=1){ s += __shfl_xor(s,off); q += __shfl_xor(q,off); }
    float mu  = s*(1.f/512.f);
    float var = fmaf(q, (1.f/512.f), -mu*mu);
    float rs  = rsqrtf(var + 1e-5f);
    const float* zp = xz + (size_t)i*xzS + tok*1024 + 512 + d0;
    float4 z0 = *(const float4*)(zp);
    float4 z1 = *(const float4*)(zp+4);
    const float* wp = nw + (size_t)(e0+i)*512 + d0;
    const float* bp = nb + (size_t)(e0+i)*512 + d0;
    float4 w0v = *(const float4*)(wp), w1v = *(const float4*)(wp+4);
    float4 b0v = *(const float4*)(bp), b1v = *(const float4*)(bp+4);
    float cb = comb[tok*4 + e0 + i];
    float yv[8] = {y0.x,y0.y,y0.z,y0.w,y1.x,y1.y,y1.z,y1.w};
    float zv[8] = {z0.x,z0.y,z0.z,z0.w,z1.x,z1.y,z1.z,z1.w};
    float wvv[8]= {w0v.x,w0v.y,w0v.z,w0v.w,w1v.x,w1v.y,w1v.z,w1v.w};
    float bvv[8]= {b0v.x,b0v.y,b0v.z,b0v.w,b1v.x,b1v.y,b1v.z,b1v.w};
    #pragma unroll
    for (int j=0;j<8;++j){
      float ln = (yv[j]-mu)*rs*wvv[j] + bvv[j];
      acc[j] = fmaf(cb*ln, zv[j]*sigmoidf_(zv[j]), acc[j]);
    }
  }
  #pragma unroll
  for (int j=0;j<8;++j)
    atomicAdd(&out[(size_t)b*512 + d0 + j], acc[j]*(1.f/196.f));
}

extern "C" void kernel_launch(void* const* d_in, const int* in_sizes, int n_in,
                              void* d_out, int out_size, void* d_ws, size_t ws_size,
                              hipStream_t stream)
{
  const float* x    = (const float*)d_in[0];
  const float* eq   = (const float*)d_in[1];
  const float* temp = (const float*)d_in[2];
  const float* ipw  = (const float*)d_in[3];
  const float* cw   = (const float*)d_in[4];
  const float* cb   = (const float*)d_in[5];
  const float* xpw  = (const float*)d_in[6];
  const float* dtw  = (const float*)d_in[7];
  const float* dtb  = (const float*)d_in[8];
  const float* alog = (const float*)d_in[9];
  const float* dsp  = (const float*)d_in[10];
  const float* nw   = (const float*)d_in[11];
  const float* nb   = (const float*)d_in[12];
  float* out = (float*)d_out;

  float* ws      = (float*)d_ws;
  float* comb    = ws;                    // 25088
  float* avgsum  = ws + 25088;            // 4
  float* loadsum = ws + 25092;            // 4

  (void)hipMemsetAsync(avgsum, 0, 8*sizeof(float), stream);
  (void)hipMemsetAsync(d_out, 0, (size_t)out_size*sizeof(float), stream);

  gate_kernel<<<dim3(1568), dim3(256), 0, stream>>>(x, eq, temp, comb, avgsum, loadsum);
  aux_kernel<<<dim3(1), dim3(64), 0, stream>>>(avgsum, loadsum, out + 16384);

  // tier sizes in floats
  const size_t T2 = 52007936ull;                    // batched, f32-staged gemm (~208 MB)
  const size_t T1 = T2 + 1605632ull + 1048576ull;   // + bf16 x and W buffers (~218.6 MB)

  if (ws_size >= T1 * sizeof(float)){
    float* xz = ws + 25600;               // 4 x 6,422,528
    float* xc = xz + 25690112;            // 4 x 3,211,264
    float* pj = xc + 12845056;            // 4 x   150,528
    float* yc = pj + 602112;              // 4 x 3,211,264
    unsigned short* xb = (unsigned short*)(yc + 12845056);   // 3,211,264 ushort
    unsigned short* wb = xb + 3211264;                       // 2,097,152 ushort
    cvt_bf16_kernel<<<dim3(512), dim3(256), 0, stream>>>(x,   xb, 401408);
    cvt_bf16_kernel<<<dim3(512), dim3(256), 0, stream>>>(ipw, wb, 262144);
    gemm_bf16<<<dim3(49,8,4), dim3(256), 0, stream>>>(xb, wb, xz);
    convproj_kernel<<<dim3(1792), dim3(512), 0, stream>>>(xz, cw, cb, xpw, xc, pj,
                                                          6422528, 3211264, 150528);
    scan_kernel<<<dim3(1024), dim3(256), 0, stream>>>(xc, pj, alog, dsp, dtw, dtb, yc,
                                                      3211264, 150528, 3211264);
    final_kernel<4><<<dim3(32,49), dim3(256), 0, stream>>>(yc, 3211264, xz, 6422528,
                                                           comb, nw, nb, out, 0);
  } else if (ws_size >= T2 * sizeof(float)){
    float* xz = ws + 25600;
    float* xc = xz + 25690112;
    float* pj = xc + 12845056;
    float* yc = pj + 602112;
    gemm_mfma<<<dim3(98,16,4), dim3(256), 0, stream>>>(x, ipw, xz, 524288, 6422528);
    convproj_kernel<<<dim3(1792), dim3(512), 0, stream>>>(xz, cw, cb, xpw, xc, pj,
                                                          6422528, 3211264, 150528);
    scan_kernel<<<dim3(1024), dim3(256), 0, stream>>>(xc, pj, alog, dsp, dtw, dtb, yc,
                                                      3211264, 150528, 3211264);
    final_kernel<4><<<dim3(32,49), dim3(256), 0, stream>>>(yc, 3211264, xz, 6422528,
                                                           comb, nw, nb, out, 0);
  } else {
    float* xz = ws + 25600;
    float* xc = xz + 6422528;
    float* pj = xc + 3211264;
    float* yc = pj + 150528;
    for (int e=0; e<4; ++e){
      gemm_mfma<<<dim3(98,16,1), dim3(256), 0, stream>>>(x, ipw + (size_t)e*524288, xz, 0, 0);
      convproj_kernel<<<dim3(448), dim3(512), 0, stream>>>(xz, cw + (size_t)e*4608,
          cb + (size_t)e*512, xpw + (size_t)e*12288, xc, pj, 0, 0, 0);
      scan_kernel<<<dim3(256), dim3(256), 0, stream>>>(xc, pj,
          alog + (size_t)e*2048, dsp + (size_t)e*2048,
          dtw + (size_t)e*8192, dtb + (size_t)e*2048, yc, 0, 0, 0);
      final_kernel<1><<<dim3(32,49), dim3(256), 0, stream>>>(yc, 0, xz, 0, comb, nw, nb, out, e);
    }
  }
}

// Round 13
// 527.446 us; speedup vs baseline: 1.1782x; 1.1782x over previous
//
#include <hip/hip_runtime.h>
#include <math.h>

#define NTOK 6272   // B*H*W = 32*14*14

typedef __attribute__((ext_vector_type(8))) short short8;
typedef __attribute__((ext_vector_type(8))) unsigned short ushort8;
typedef __attribute__((ext_vector_type(4))) float f32x4;

__device__ __forceinline__ float sigmoidf_(float v){ return 1.0f/(1.0f + expf(-v)); }

// f32 -> bf16 round-to-nearest-even
__device__ __forceinline__ unsigned short f2b(float f){
  union { float f; unsigned u; } v; v.f = f;
  unsigned r = (v.u + 0x7fffu + ((v.u>>16)&1u)) >> 16;
  return (unsigned short)r;
}

// ---------------- f32 -> bf16 bulk convert (grid-stride, vectorized) ----------------
__global__ __launch_bounds__(256) void cvt_bf16_kernel(
    const float* __restrict__ src, unsigned short* __restrict__ dst, int n8)
{
  int i = blockIdx.x*256 + threadIdx.x;
  int stride = gridDim.x*256;
  for (; i < n8; i += stride){
    float4 a = *(const float4*)(src + (size_t)i*8);
    float4 b = *(const float4*)(src + (size_t)i*8 + 4);
    ushort8 o;
    o[0]=f2b(a.x); o[1]=f2b(a.y); o[2]=f2b(a.z); o[3]=f2b(a.w);
    o[4]=f2b(b.x); o[5]=f2b(b.y); o[6]=f2b(b.z); o[7]=f2b(b.w);
    *(ushort8*)(dst + (size_t)i*8) = o;
  }
}

// ---------------- gating: logits -> softmax -> top2 -> comb + avg/load sums ----------------
__global__ __launch_bounds__(256) void gate_kernel(
    const float* __restrict__ x, const float* __restrict__ eq,
    const float* __restrict__ temp, float* __restrict__ comb,
    float* __restrict__ avgsum, float* __restrict__ loadsum)
{
  __shared__ float lacc[8];
  if (threadIdx.x < 8) lacc[threadIdx.x] = 0.f;
  __syncthreads();
  int wid = threadIdx.x >> 6, lane = threadIdx.x & 63;
  int m = blockIdx.x*4 + wid;             // token index
  const float* xr = x + (size_t)m*512;
  float a0=0.f,a1=0.f,a2=0.f,a3=0.f;
  #pragma unroll
  for (int j=0;j<8;++j){
    float xv = xr[j*64+lane];
    a0 = fmaf(xv, eq[0*512 + j*64+lane], a0);
    a1 = fmaf(xv, eq[1*512 + j*64+lane], a1);
    a2 = fmaf(xv, eq[2*512 + j*64+lane], a2);
    a3 = fmaf(xv, eq[3*512 + j*64+lane], a3);
  }
  #pragma unroll
  for (int off=32; off; off>>=1){
    a0 += __shfl_xor(a0,off); a1 += __shfl_xor(a1,off);
    a2 += __shfl_xor(a2,off); a3 += __shfl_xor(a3,off);
  }
  if (lane == 0){
    float T = temp[0];
    float l0=a0/T, l1=a1/T, l2=a2/T, l3=a3/T;
    float mx = fmaxf(fmaxf(l0,l1), fmaxf(l2,l3));
    float e0=expf(l0-mx), e1=expf(l1-mx), e2=expf(l2-mx), e3=expf(l3-mx);
    float s = e0+e1+e2+e3;
    float g0=e0/s, g1=e1/s, g2=e2/s, g3=e3/s;
    int i1=0; float v1=g0;
    if (g1>v1){v1=g1;i1=1;}
    if (g2>v1){v1=g2;i1=2;}
    if (g3>v1){v1=g3;i1=3;}
    int i2=-1; float v2=-2.f;
    if (i1!=0)          {v2=g0;i2=0;}
    if (i1!=1 && g1>v2) {v2=g1;i2=1;}
    if (i1!=2 && g2>v2) {v2=g2;i2=2;}
    if (i1!=3 && g3>v2) {v2=g3;i2=3;}
    float inv = 1.f/(v1+v2);
    float c0 = (i1==0)? v1*inv : ((i2==0)? v2*inv : 0.f);
    float c1 = (i1==1)? v1*inv : ((i2==1)? v2*inv : 0.f);
    float c2 = (i1==2)? v1*inv : ((i2==2)? v2*inv : 0.f);
    float c3 = (i1==3)? v1*inv : ((i2==3)? v2*inv : 0.f);
    comb[(size_t)m*4+0]=c0; comb[(size_t)m*4+1]=c1;
    comb[(size_t)m*4+2]=c2; comb[(size_t)m*4+3]=c3;
    atomicAdd(&lacc[0], g0); atomicAdd(&lacc[1], g1);
    atomicAdd(&lacc[2], g2); atomicAdd(&lacc[3], g3);
    atomicAdd(&lacc[4+i1], 0.5f);
    atomicAdd(&lacc[4+i2], 0.5f);
  }
  __syncthreads();
  if (threadIdx.x < 4){
    atomicAdd(&avgsum[threadIdx.x],  lacc[threadIdx.x]);
    atomicAdd(&loadsum[threadIdx.x], lacc[4+threadIdx.x]);
  }
}

__global__ void aux_kernel(const float* __restrict__ avgsum,
                           const float* __restrict__ loadsum,
                           float* __restrict__ out_aux)
{
  if (threadIdx.x == 0 && blockIdx.x == 0){
    float s = 0.f;
    #pragma unroll
    for (int e=0;e<4;++e)
      s += (avgsum[e]/(float)NTOK) * (loadsum[e]/(float)NTOK);
    out_aux[0] = 0.01f * (s * 0.25f) * 16.0f;
  }
}

// ---------------- in_proj GEMM, bf16 inputs, 128x128 tile (tier 0/1) ----------------
__global__ __launch_bounds__(256) void gemm_bf16(
    const unsigned short* __restrict__ A, const unsigned short* __restrict__ W,
    float* __restrict__ C)
{
  __shared__ unsigned short As[128][56];
  __shared__ unsigned short Bs[128][56];
  const unsigned short* We = W + (size_t)blockIdx.z*524288;
  float* Ce = C + (size_t)blockIdx.z*6422528;
  int m0 = blockIdx.x*128, n0 = blockIdx.y*128;
  int t = threadIdx.x;
  int srow = t>>1, scol = (t&1)*16;
  int w = t>>6, lane = t&63;
  int wr = (w>>1)*64, wc = (w&1)*64;
  int fr = lane&15, fk = (lane>>4)*8;
  f32x4 acc[4][4] = {};
  const unsigned short* ap = A  + (size_t)(m0+srow)*512 + scol;
  const unsigned short* bp = We + (size_t)(n0+srow)*512 + scol;
  for (int k0=0; k0<512; k0+=32){
    ushort8 va0 = *(const ushort8*)(ap+k0);
    ushort8 va1 = *(const ushort8*)(ap+k0+8);
    ushort8 vb0 = *(const ushort8*)(bp+k0);
    ushort8 vb1 = *(const ushort8*)(bp+k0+8);
    __syncthreads();
    *(ushort8*)&As[srow][scol]   = va0;
    *(ushort8*)&As[srow][scol+8] = va1;
    *(ushort8*)&Bs[srow][scol]   = vb0;
    *(ushort8*)&Bs[srow][scol+8] = vb1;
    __syncthreads();
    short8 af[4], bf[4];
    #pragma unroll
    for (int i=0;i<4;++i){
      af[i] = *(short8*)&As[wr+i*16+fr][fk];
      bf[i] = *(short8*)&Bs[wc+i*16+fr][fk];
    }
    #pragma unroll
    for (int i=0;i<4;++i)
      #pragma unroll
      for (int j=0;j<4;++j)
        acc[i][j] = __builtin_amdgcn_mfma_f32_16x16x32_bf16(af[i],bf[j],acc[i][j],0,0,0);
  }
  int orow = (lane>>4)*4;   // C/D: col=lane&15, row=(lane>>4)*4+reg  [m89-verified]
  #pragma unroll
  for (int i=0;i<4;++i)
    #pragma unroll
    for (int j=0;j<4;++j)
      #pragma unroll
      for (int r=0;r<4;++r)
        Ce[(size_t)(m0+wr+i*16+orow+r)*1024 + n0+wc+j*16+fr] = acc[i][j][r];
}

// ---------------- in_proj GEMM, in-loop f32->bf16 (tier 2/3 fallback) ----------------
__global__ __launch_bounds__(256) void gemm_mfma(
    const float* __restrict__ A, const float* __restrict__ W,
    float* __restrict__ C, size_t wStride, size_t cStride)
{
  __shared__ unsigned short As[64][56];
  __shared__ unsigned short Bs[64][56];
  const float* We = W + (size_t)blockIdx.z*wStride;
  float* Ce = C + (size_t)blockIdx.z*cStride;
  int m0 = blockIdx.x*64, n0 = blockIdx.y*64;
  int t = threadIdx.x;
  int srow = t>>2, scol = (t&3)*8;
  int w = t>>6, lane = t&63;
  int wr = (w>>1)*32, wc = (w&1)*32;
  int fr = lane&15, fk = (lane>>4)*8;
  f32x4 acc00={0.f,0.f,0.f,0.f}, acc01={0.f,0.f,0.f,0.f};
  f32x4 acc10={0.f,0.f,0.f,0.f}, acc11={0.f,0.f,0.f,0.f};
  const float* ap = A  + (size_t)(m0+srow)*512 + scol;
  const float* bp = We + (size_t)(n0+srow)*512 + scol;
  for (int k0=0; k0<512; k0+=32){
    float4 av0 = *(const float4*)(ap+k0);
    float4 av1 = *(const float4*)(ap+k0+4);
    float4 bv0 = *(const float4*)(bp+k0);
    float4 bv1 = *(const float4*)(bp+k0+4);
    ushort8 va, vb;
    va[0]=f2b(av0.x); va[1]=f2b(av0.y); va[2]=f2b(av0.z); va[3]=f2b(av0.w);
    va[4]=f2b(av1.x); va[5]=f2b(av1.y); va[6]=f2b(av1.z); va[7]=f2b(av1.w);
    vb[0]=f2b(bv0.x); vb[1]=f2b(bv0.y); vb[2]=f2b(bv0.z); vb[3]=f2b(bv0.w);
    vb[4]=f2b(bv1.x); vb[5]=f2b(bv1.y); vb[6]=f2b(bv1.z); vb[7]=f2b(bv1.w);
    __syncthreads();
    *(ushort8*)&As[srow][scol] = va;
    *(ushort8*)&Bs[srow][scol] = vb;
    __syncthreads();
    short8 a0 = *(short8*)&As[wr+fr][fk];
    short8 a1 = *(short8*)&As[wr+16+fr][fk];
    short8 b0 = *(short8*)&Bs[wc+fr][fk];
    short8 b1 = *(short8*)&Bs[wc+16+fr][fk];
    acc00 = __builtin_amdgcn_mfma_f32_16x16x32_bf16(a0,b0,acc00,0,0,0);
    acc01 = __builtin_amdgcn_mfma_f32_16x16x32_bf16(a0,b1,acc01,0,0,0);
    acc10 = __builtin_amdgcn_mfma_f32_16x16x32_bf16(a1,b0,acc10,0,0,0);
    acc11 = __builtin_amdgcn_mfma_f32_16x16x32_bf16(a1,b1,acc11,0,0,0);
  }
  int orow = (lane>>4)*4;
  #pragma unroll
  for (int r=0;r<4;++r){
    Ce[(size_t)(m0+wr+orow+r)*1024    + n0+wc+fr]    = acc00[r];
    Ce[(size_t)(m0+wr+orow+r)*1024    + n0+wc+16+fr] = acc01[r];
    Ce[(size_t)(m0+wr+16+orow+r)*1024 + n0+wc+fr]    = acc10[r];
    Ce[(size_t)(m0+wr+16+orow+r)*1024 + n0+wc+16+fr] = acc11[r];
  }
}

// ---------------- fused conv+proj, row-block form with XCD-chunked swizzle ----------------
__global__ __launch_bounds__(512) void convproj_kernel(
    const float* __restrict__ xz, const float* __restrict__ cw,
    const float* __restrict__ cb, const float* __restrict__ xw,
    float* __restrict__ xc, float* __restrict__ proj,
    size_t xzS, size_t xcS, size_t prS)
{
  __shared__ float sact[512];
  int chunk = gridDim.x >> 3;                    // grid divisible by 8
  int bid = blockIdx.x;
  int flat = (bid & 7)*chunk + (bid >> 3);       // XCD-chunked swizzle (bijective)
  int h  = flat % 14;
  int be = flat / 14;
  int b  = be & 31;
  int e  = be >> 5;
  const float* xze = xz + (size_t)e*xzS;
  const float* cwe = cw + (size_t)e*4608;
  const float* xwe = xw + (size_t)e*12288;
  float* xce = xc + (size_t)e*xcS;
  float* pre = proj + (size_t)e*prS;
  int d = threadIdx.x;
  int wv = d>>6, lane = d&63;
  int d0 = lane*8;

  float wreg[9];
  #pragma unroll
  for (int i=0;i<9;++i) wreg[i] = cwe[d*9+i];
  float bias = cb[(size_t)e*512 + d];

  const float* base = xze + ((size_t)b*196 + (size_t)h*14)*1024 + d;

  for (int w=0; w<14; ++w){
    float s = bias;
    #pragma unroll
    for (int dh=-1; dh<=1; ++dh){
      int hh = h+dh; if ((unsigned)hh >= 14u) continue;
      #pragma unroll
      for (int dw=-1; dw<=1; ++dw){
        int ww = w+dw; if ((unsigned)ww >= 14u) continue;
        s = fmaf(base[(ptrdiff_t)(dh*14 + ww)*1024], wreg[(dh+1)*3 + (dw+1)], s);
      }
    }
    float sa = s * sigmoidf_(s);
    size_t m = (size_t)b*196 + h*14 + w;
    xce[m*512 + d] = sa;
    __syncthreads();
    sact[d] = sa;
    __syncthreads();
    float4 v0 = *(const float4*)&sact[d0];
    float4 v1 = *(const float4*)&sact[d0+4];
    #pragma unroll
    for (int j=0;j<3;++j){
      int kc = wv*3 + j;
      const float* wr = xwe + (size_t)kc*512 + d0;
      float4 w0 = *(const float4*)(wr);
      float4 w1 = *(const float4*)(wr+4);
      float a = v0.x*w0.x + v0.y*w0.y + v0.z*w0.z + v0.w*w0.w
              + v1.x*w1.x + v1.y*w1.y + v1.z*w1.z + v1.w*w1.w;
      #pragma unroll
      for (int off=32; off; off>>=1) a += __shfl_xor(a,off);
      if (lane==0) pre[m*24 + kc] = a;
    }
  }
}

#define WRAP(v) ((v) > 195 ? (v)-195 : ((v) < 0 ? (v)+195 : (v)))

// ---------------- scan, split output: ydir[e][k][tok][d], plain stores, no atomics ----------------
__global__ __launch_bounds__(256) void scan_split(
    const float* __restrict__ xc, const float* __restrict__ proj,
    const float* __restrict__ Alogs, const float* __restrict__ Dsp,
    const float* __restrict__ dtw, const float* __restrict__ dtb,
    float* __restrict__ ydir, size_t xcS, size_t prS)
{
  const float LN2 = 0.6931471805599453f;
  int g = blockIdx.x*256 + threadIdx.x;
  int e  = g >> 16;
  int ge = g & 65535;
  int d = ge & 511;
  int k = (ge >> 9) & 3;
  int b = ge >> 11;
  const float* xce = xc + (size_t)e*xcS;
  const float* pre = proj + (size_t)e*prS;
  int eo = e*2048;
  float Ak  = -__expf(Alogs[eo + k*512 + d]);
  float Dk  = Dsp[eo + k*512 + d];
  float btk = dtb[eo + k*512 + d];
  const float* wr = dtw + (size_t)e*8192 + ((size_t)(k*512 + d))*4;
  float w0=wr[0], w1=wr[1], w2=wr[2], w3=wr[3];
  float hst = 0.f;
  const float* xcb = xce + (size_t)b*196*512 + d;
  const float* pb  = pre + (size_t)b*196*24 + k*6;
  float* yb = ydir + ((size_t)(e*4 + k))*3211264 + (size_t)b*196*512 + d;

  int step = (k==0)? 1 : (k==1)? -1 : (k==2)? 14 : -14;
  int t0   = (k==0 || k==2)? 0 : 195;

  int ta=t0, tb_=WRAP(ta+step), tc=WRAP(tb_+step), td_=WRAP(tc+step);
  float  xa=xcb[ta*512],  xb=xcb[tb_*512],  xcv=xcb[tc*512],  xd=xcb[td_*512];
  float2 a0=*(const float2*)(pb+ta*24),  a1=*(const float2*)(pb+ta*24+2),  a2=*(const float2*)(pb+ta*24+4);
  float2 b0=*(const float2*)(pb+tb_*24), b1=*(const float2*)(pb+tb_*24+2), b2=*(const float2*)(pb+tb_*24+4);
  float2 c0=*(const float2*)(pb+tc*24),  c1=*(const float2*)(pb+tc*24+2),  c2=*(const float2*)(pb+tc*24+4);
  float2 d0=*(const float2*)(pb+td_*24), d1=*(const float2*)(pb+td_*24+2), d2=*(const float2*)(pb+td_*24+4);

#define STEP(tt, xv, f0, f1, f2)                                              \
  {                                                                           \
    float dtraw = btk + w0*f0.x + w1*f0.y + w2*f1.x + w3*f1.y;                \
    float sp = fmaxf(dtraw, 0.f) + LN2*__log2f(1.0f + __expf(-fabsf(dtraw))); \
    float dA = __expf(sp*Ak);                                                 \
    hst = fmaf(dA, hst, sp*xv*f2.x);                                          \
    yb[(tt)*512] = fmaf(hst, f2.y, xv*Dk);                                    \
  }

  for (int gg=0; gg<48; ++gg){
    int na = WRAP(td_+step), nb = WRAP(na+step), nc = WRAP(nb+step), nd = WRAP(nc+step);
    float  nxa=xcb[na*512], nxb=xcb[nb*512], nxc=xcb[nc*512], nxd=xcb[nd*512];
    float2 qa0=*(const float2*)(pb+na*24), qa1=*(const float2*)(pb+na*24+2), qa2=*(const float2*)(pb+na*24+4);
    float2 qb0=*(const float2*)(pb+nb*24), qb1=*(const float2*)(pb+nb*24+2), qb2=*(const float2*)(pb+nb*24+4);
    float2 qc0=*(const float2*)(pb+nc*24), qc1=*(const float2*)(pb+nc*24+2), qc2=*(const float2*)(pb+nc*24+4);
    float2 qd0=*(const float2*)(pb+nd*24), qd1=*(const float2*)(pb+nd*24+2), qd2=*(const float2*)(pb+nd*24+4);

    STEP(ta, xa, a0, a1, a2)
    STEP(tb_, xb, b0, b1, b2)
    STEP(tc, xcv, c0, c1, c2)
    STEP(td_, xd, d0, d1, d2)

    ta=na; tb_=nb; tc=nc; td_=nd;
    xa=nxa; xb=nxb; xcv=nxc; xd=nxd;
    a0=qa0; a1=qa1; a2=qa2;
    b0=qb0; b1=qb1; b2=qb2;
    c0=qc0; c1=qc1; c2=qc2;
    d0=qd0; d1=qd1; d2=qd2;
  }
  STEP(ta, xa, a0, a1, a2)
  STEP(tb_, xb, b0, b1, b2)
  STEP(tc, xcv, c0, c1, c2)
  STEP(td_, xd, d0, d1, d2)
#undef STEP
}

// ---------------- scan, merged output via global atomics (tier 1/2/3 fallback, R9-proven) ----------------
__global__ __launch_bounds__(256) void scan_atomic(
    const float* __restrict__ xc, const float* __restrict__ proj,
    const float* __restrict__ Alogs, const float* __restrict__ Dsp,
    const float* __restrict__ dtw, const float* __restrict__ dtb,
    float* __restrict__ ycomb, size_t xcS, size_t prS, size_t ycS)
{
  const float LN2 = 0.6931471805599453f;
  int g = blockIdx.x*256 + threadIdx.x;
  int e  = g >> 16;
  int ge = g & 65535;
  int d = ge & 511;
  int k = (ge >> 9) & 3;
  int b = ge >> 11;
  const float* xce = xc + (size_t)e*xcS;
  const float* pre = proj + (size_t)e*prS;
  float* yce = ycomb + (size_t)e*ycS;
  int eo = e*2048;
  float Ak  = -__expf(Alogs[eo + k*512 + d]);
  float Dk  = Dsp[eo + k*512 + d];
  float btk = dtb[eo + k*512 + d];
  const float* wr = dtw + (size_t)e*8192 + ((size_t)(k*512 + d))*4;
  float w0=wr[0], w1=wr[1], w2=wr[2], w3=wr[3];
  float hst = 0.f;
  const float* xcb = xce + (size_t)b*196*512 + d;
  const float* pb  = pre + (size_t)b*196*24 + k*6;
  float* yb = yce + (size_t)b*196*512 + d;

  int step = (k==0)? 1 : (k==1)? -1 : (k==2)? 14 : -14;
  int t = (k==0 || k==2)? 0 : 195;
  float xval = xcb[t*512];
  const float* pp = pb + t*24;
  float p0=pp[0], p1=pp[1], p2=pp[2], p3=pp[3], Bsv=pp[4], Csv=pp[5];

  for (int l=0; l<196; ++l){
    int tn = WRAP(t + step);
    float xval_n = xcb[tn*512];
    const float* ppn = pb + tn*24;
    float q0=ppn[0], q1=ppn[1], q2=ppn[2], q3=ppn[3], Bn_=ppn[4], Cn_=ppn[5];
    float dtraw = btk + w0*p0 + w1*p1 + w2*p2 + w3*p3;
    float sp = fmaxf(dtraw, 0.f) + LN2*__log2f(1.0f + __expf(-fabsf(dtraw)));
    float dA = __expf(sp*Ak);
    hst = fmaf(dA, hst, sp*xval*Bsv);
    float y = fmaf(hst, Csv, xval*Dk);
    atomicAdd(&yb[t*512], y);
    t = tn; xval = xval_n;
    p0=q0; p1=q1; p2=q2; p3=q3; Bsv=Bn_; Csv=Cn_;
  }
}

// ---------------- LayerNorm + SiLU(z) gate + comb mix + token-mean (wave-per-token) ----------------
// NDIR=4: y summed from 4 per-direction buffers (stride kS); NDIR=1: pre-merged.
template<int NEXP, int NDIR>
__global__ __launch_bounds__(256) void final_kernel(
    const float* __restrict__ ycomb, size_t eS, size_t kS,
    const float* __restrict__ xz, size_t xzS,
    const float* __restrict__ comb, const float* __restrict__ nw,
    const float* __restrict__ nb, float* __restrict__ out, int e0)
{
  int b = blockIdx.x;
  int wv = threadIdx.x>>6, lane = threadIdx.x&63;
  int t = blockIdx.y*4 + wv;             // 49*4 = 196 tokens
  size_t tok = (size_t)b*196 + t;
  int d0 = lane*8;
  float acc[8] = {0.f,0.f,0.f,0.f,0.f,0.f,0.f,0.f};
  #pragma unroll
  for (int i=0;i<NEXP;++i){
    float yv[8] = {0.f,0.f,0.f,0.f,0.f,0.f,0.f,0.f};
    #pragma unroll
    for (int kk=0;kk<NDIR;++kk){
      const float* yp = ycomb + (size_t)i*eS + (size_t)kk*kS + tok*512 + d0;
      float4 y0 = *(const float4*)(yp);
      float4 y1 = *(const float4*)(yp+4);
      yv[0]+=y0.x; yv[1]+=y0.y; yv[2]+=y0.z; yv[3]+=y0.w;
      yv[4]+=y1.x; yv[5]+=y1.y; yv[6]+=y1.z; yv[7]+=y1.w;
    }
    float s=0.f, q=0.f;
    #pragma unroll
    for (int j=0;j<8;++j){ s += yv[j]; q += yv[j]*yv[j]; }
    #pragma unroll
    for (int off=32; off; off>>=1){ s += __shfl_xor(s,off); q += __shfl_xor(q,off); }
    float mu  = s*(1.f/512.f);
    float var = fmaf(q, (1.f/512.f), -mu*mu);
    float rs  = rsqrtf(var + 1e-5f);
    const float* zp = xz + (size_t)i*xzS + tok*1024 + 512 + d0;
    float4 z0 = *(const float4*)(zp);
    float4 z1 = *(const float4*)(zp+4);
    const float* wp = nw + (size_t)(e0+i)*512 + d0;
    const float* bp = nb + (size_t)(e0+i)*512 + d0;
    float4 w0v = *(const float4*)(wp), w1v = *(const float4*)(wp+4);
    float4 b0v = *(const float4*)(bp), b1v = *(const float4*)(bp+4);
    float cbv = comb[tok*4 + e0 + i];
    float zv[8] = {z0.x,z0.y,z0.z,z0.w,z1.x,z1.y,z1.z,z1.w};
    float wvv[8]= {w0v.x,w0v.y,w0v.z,w0v.w,w1v.x,w1v.y,w1v.z,w1v.w};
    float bvv[8]= {b0v.x,b0v.y,b0v.z,b0v.w,b1v.x,b1v.y,b1v.z,b1v.w};
    #pragma unroll
    for (int j=0;j<8;++j){
      float ln = (yv[j]-mu)*rs*wvv[j] + bvv[j];
      acc[j] = fmaf(cbv*ln, zv[j]*sigmoidf_(zv[j]), acc[j]);
    }
  }
  #pragma unroll
  for (int j=0;j<8;++j)
    atomicAdd(&out[(size_t)b*512 + d0 + j], acc[j]*(1.f/196.f));
}

extern "C" void kernel_launch(void* const* d_in, const int* in_sizes, int n_in,
                              void* d_out, int out_size, void* d_ws, size_t ws_size,
                              hipStream_t stream)
{
  const float* x    = (const float*)d_in[0];
  const float* eq   = (const float*)d_in[1];
  const float* temp = (const float*)d_in[2];
  const float* ipw  = (const float*)d_in[3];
  const float* cw   = (const float*)d_in[4];
  const float* cb   = (const float*)d_in[5];
  const float* xpw  = (const float*)d_in[6];
  const float* dtw  = (const float*)d_in[7];
  const float* dtb  = (const float*)d_in[8];
  const float* alog = (const float*)d_in[9];
  const float* dsp  = (const float*)d_in[10];
  const float* nw   = (const float*)d_in[11];
  const float* nb   = (const float*)d_in[12];
  float* out = (float*)d_out;

  float* ws      = (float*)d_ws;
  float* comb    = ws;                    // 25088
  float* avgsum  = ws + 25088;            // 4
  float* loadsum = ws + 25092;            // 4

  (void)hipMemsetAsync(avgsum, 0, 8*sizeof(float), stream);
  (void)hipMemsetAsync(d_out, 0, (size_t)out_size*sizeof(float), stream);

  gate_kernel<<<dim3(1568), dim3(256), 0, stream>>>(x, eq, temp, comb, avgsum, loadsum);
  aux_kernel<<<dim3(1), dim3(64), 0, stream>>>(avgsum, loadsum, out + 16384);

  // tier sizes in floats
  const size_t T2 = 52007936ull;                      // batched, f32-staged gemm (~208 MB)
  const size_t T1 = T2 + 1605632ull + 1048576ull;     // + bf16 x/W buffers (~218.6 MB)
  const size_t T0 = T1 + 38535168ull;                 // + split-direction ydir (~372.8 MB)

  if (ws_size >= T0 * sizeof(float)){
    float* xz   = ws + 25600;             // 4 x 6,422,528
    float* xc   = xz + 25690112;          // 4 x 3,211,264
    float* pj   = xc + 12845056;          // 4 x   150,528
    float* ydir = pj + 602112;            // 16 x 3,211,264 (e-major, k-minor)
    unsigned short* xb = (unsigned short*)(ydir + 51380224);  // 3,211,264 ushort
    unsigned short* wb = xb + 3211264;                        // 2,097,152 ushort
    cvt_bf16_kernel<<<dim3(512), dim3(256), 0, stream>>>(x,   xb, 401408);
    cvt_bf16_kernel<<<dim3(512), dim3(256), 0, stream>>>(ipw, wb, 262144);
    gemm_bf16<<<dim3(49,8,4), dim3(256), 0, stream>>>(xb, wb, xz);
    convproj_kernel<<<dim3(1792), dim3(512), 0, stream>>>(xz, cw, cb, xpw, xc, pj,
                                                          6422528, 3211264, 150528);
    scan_split<<<dim3(1024), dim3(256), 0, stream>>>(xc, pj, alog, dsp, dtw, dtb, ydir,
                                                     3211264, 150528);
    final_kernel<4,4><<<dim3(32,49), dim3(256), 0, stream>>>(ydir, 12845056, 3211264,
                                                             xz, 6422528, comb, nw, nb, out, 0);
  } else if (ws_size >= T1 * sizeof(float)){
    float* xz = ws + 25600;
    float* xc = xz + 25690112;
    float* pj = xc + 12845056;
    float* yc = pj + 602112;
    unsigned short* xb = (unsigned short*)(yc + 12845056);
    unsigned short* wb = xb + 3211264;
    cvt_bf16_kernel<<<dim3(512), dim3(256), 0, stream>>>(x,   xb, 401408);
    cvt_bf16_kernel<<<dim3(512), dim3(256), 0, stream>>>(ipw, wb, 262144);
    gemm_bf16<<<dim3(49,8,4), dim3(256), 0, stream>>>(xb, wb, xz);
    convproj_kernel<<<dim3(1792), dim3(512), 0, stream>>>(xz, cw, cb, xpw, xc, pj,
                                                          6422528, 3211264, 150528);
    (void)hipMemsetAsync(yc, 0, 12845056ull*sizeof(float), stream);
    scan_atomic<<<dim3(1024), dim3(256), 0, stream>>>(xc, pj, alog, dsp, dtw, dtb, yc,
                                                      3211264, 150528, 3211264);
    final_kernel<4,1><<<dim3(32,49), dim3(256), 0, stream>>>(yc, 3211264, 0,
                                                             xz, 6422528, comb, nw, nb, out, 0);
  } else if (ws_size >= T2 * sizeof(float)){
    float* xz = ws + 25600;
    float* xc = xz + 25690112;
    float* pj = xc + 12845056;
    float* yc = pj + 602112;
    gemm_mfma<<<dim3(98,16,4), dim3(256), 0, stream>>>(x, ipw, xz, 524288, 6422528);
    convproj_kernel<<<dim3(1792), dim3(512), 0, stream>>>(xz, cw, cb, xpw, xc, pj,
                                                          6422528, 3211264, 150528);
    (void)hipMemsetAsync(yc, 0, 12845056ull*sizeof(float), stream);
    scan_atomic<<<dim3(1024), dim3(256), 0, stream>>>(xc, pj, alog, dsp, dtw, dtb, yc,
                                                      3211264, 150528, 3211264);
    final_kernel<4,1><<<dim3(32,49), dim3(256), 0, stream>>>(yc, 3211264, 0,
                                                             xz, 6422528, comb, nw, nb, out, 0);
  } else {
    float* xz = ws + 25600;
    float* xc = xz + 6422528;
    float* pj = xc + 3211264;
    float* yc = pj + 150528;
    for (int e=0; e<4; ++e){
      gemm_mfma<<<dim3(98,16,1), dim3(256), 0, stream>>>(x, ipw + (size_t)e*524288, xz, 0, 0);
      convproj_kernel<<<dim3(448), dim3(512), 0, stream>>>(xz, cw + (size_t)e*4608,
          cb + (size_t)e*512, xpw + (size_t)e*12288, xc, pj, 0, 0, 0);
      (void)hipMemsetAsync(yc, 0, 3211264ull*sizeof(float), stream);
      scan_atomic<<<dim3(256), dim3(256), 0, stream>>>(xc, pj,
          alog + (size_t)e*2048, dsp + (size_t)e*2048,
          dtw + (size_t)e*8192, dtb + (size_t)e*2048, yc, 0, 0, 0);
      final_kernel<1,1><<<dim3(32,49), dim3(256), 0, stream>>>(yc, 0, 0, xz, 0,
                                                               comb, nw, nb, out, e);
    }
  }
}